// Round 2
// 281.711 us; speedup vs baseline: 1.0757x; 1.0757x over previous
//
#include <hip/hip_runtime.h>

using u16 = unsigned short;
using u32 = unsigned int;

// Problem constants: B=8, T=2048, C=1024
constexpr int Cdim  = 1024;
constexpr int Bn    = 8;
constexpr int Tn    = 2048;
constexpr int Mrows = Bn * Tn;          // 16384 rows in all GEMMs
constexpr int NCH   = 16;               // wkv chunks per chain
constexpr int CLEN  = Tn / NCH;         // 128 steps per chunk

// ---------- bf16 helpers (bit-level, RNE) ----------
__device__ inline u16 f2bf(float x) {
    u32 u = __float_as_uint(x);
    u += 0x7fffu + ((u >> 16) & 1u);
    return (u16)(u >> 16);
}
__device__ inline float bf2f(u16 x) {
    return __uint_as_float(((u32)x) << 16);
}

// ---------- fp32 -> bf16 cast: X (large) ----------
__global__ __launch_bounds__(256)
void cast_f32_bf16(const float* __restrict__ in, u16* __restrict__ out, int n4) {
    int i = blockIdx.x * 256 + threadIdx.x;
    if (i < n4) {
        float4 v = ((const float4*)in)[i];
        ushort4 o;
        o.x = f2bf(v.x); o.y = f2bf(v.y); o.z = f2bf(v.z); o.w = f2bf(v.w);
        ((ushort4*)out)[i] = o;
    }
}

// ---------- fp32 -> bf16 cast: 3 weight matrices in one dispatch ----------
// o0/o1 are the two halves of the concatenated [Wv; Wr] (2048 x 1024)
__global__ __launch_bounds__(256)
void cast_weights(const float* __restrict__ w0, const float* __restrict__ w1,
                  const float* __restrict__ w2,
                  u16* __restrict__ o0, u16* __restrict__ o1, u16* __restrict__ o2) {
    const int i = blockIdx.x * 256 + threadIdx.x;   // 0..262143
    const float* in  = (blockIdx.y == 0) ? w0 : (blockIdx.y == 1) ? w1 : w2;
    u16*         out = (blockIdx.y == 0) ? o0 : (blockIdx.y == 1) ? o1 : o2;
    float4 v = ((const float4*)in)[i];
    ushort4 o;
    o.x = f2bf(v.x); o.y = f2bf(v.y); o.z = f2bf(v.z); o.w = f2bf(v.w);
    ((ushort4*)out)[i] = o;
}

// ---------- MFMA bf16 NT-GEMM, 256x256 tile, 8-phase pipelined ----------
typedef __bf16 bf16x8 __attribute__((ext_vector_type(8)));
typedef float  f32x4  __attribute__((ext_vector_type(4)));

#define SB0() __builtin_amdgcn_sched_barrier(0)
#define BARRIER() do { SB0(); __builtin_amdgcn_s_barrier(); SB0(); } while (0)
#define LGKM0()   do { asm volatile("s_waitcnt lgkmcnt(0)" ::: "memory"); SB0(); } while (0)
#define VMW(n)    do { asm volatile("s_waitcnt vmcnt(" #n ")" ::: "memory"); SB0(); } while (0)

__device__ __forceinline__ void gload16(const u16* g, char* l) {
    __builtin_amdgcn_global_load_lds(
        (const __attribute__((address_space(1))) void*)g,
        (__attribute__((address_space(3))) void*)l, 16, 0, 0);
}

// One C-quadrant x K=64: 16 MFMAs, setprio-wrapped (T5).
template<int IB, int JB>
__device__ __forceinline__ void mma_quad(f32x4 (&acc)[8][4],
                                         const bf16x8 (&aF)[4][2],
                                         const bf16x8 (&bF)[4][2]) {
    __builtin_amdgcn_s_setprio(1);
    #pragma unroll
    for (int i = 0; i < 4; ++i)
        #pragma unroll
        for (int j = 0; j < 2; ++j) {
            acc[IB + i][JB + j] = __builtin_amdgcn_mfma_f32_16x16x32_bf16(
                aF[i][0], bF[JB + j][0], acc[IB + i][JB + j], 0, 0, 0);
            acc[IB + i][JB + j] = __builtin_amdgcn_mfma_f32_16x16x32_bf16(
                aF[i][1], bF[JB + j][1], acc[IB + i][JB + j], 0, 0, 0);
        }
    __builtin_amdgcn_s_setprio(0);
}

// Core main loop. Tile 256x256, BK=64, K=1024 (16 K-tiles), 8 waves (2M x 4N).
// LDS (128 KiB): buf p at p*65536; A at +0 ([2 halves][2 row-blocks] of 8 KiB),
// B at +32768 same layout. Swizzle: 16B-slot s within a 128B row holds logical
// slot s ^ (row&7) -- applied on the GLOBAL source address at stage time (LDS
// dest of global_load_lds must stay linear) and on the ds_read address.
//
// Per-wave load issue order per tile: a1,a2 (ph1) b1,b2 (ph2) b3,b4 (ph3)
// a3,a4 (ph4). VMW(4) at ph2 retires A.l2(t) before ph3 reads it; VMW(2) at
// ph4 retires everything for tile t+1 except A.l2(t+1), which stays in flight
// across the tile boundary (counted-vmcnt, T4).
__device__ __forceinline__ void gemm_core(const u16* __restrict__ A,
                                          const u16* __restrict__ W,
                                          char* smem, f32x4 (&acc)[8][4],
                                          int m0, int n0, int wave, int lane)
{
    const int l15 = lane & 15;
    const int g   = lane >> 4;
    const int wr  = wave >> 2;   // 0..1  (M)
    const int wc  = wave & 3;    // 0..3  (N)
    const int tid = wave * 64 + lane;

    // ---- staging addressing (per-thread global src, wave-uniform LDS dst) ----
    const int srow = tid >> 3;                               // 0..63
    const int kcol = ((tid & 7) ^ (srow & 7)) * 8;           // pre-swizzled k-chunk
    const u16* aG = A + (size_t)(m0 + srow) * Cdim + kcol;
    const u16* bG = W + (size_t)(n0 + srow) * Cdim + kcol;
    char* stDst = smem + wave * 1024;

    // ---- fragment-read addressing (swizzled ds_read) ----
    const int x0 = (g ^ (l15 & 7)) * 16;                     // kk=0 slot byte; kk=1 -> x0^64
    const char* aRd = smem + wr * 16384 + l15 * 128;
    const char* bRd = smem + 32768 + wc * 8192 + l15 * 128;

    bf16x8 aF[4][2], bF[4][2];

    // ---- prologue: stage K-tile 0 into buf0 ----
    gload16(aG,                    stDst);                       // A.h0.l1
    gload16(aG + 128 * Cdim,       stDst + 16384);               // A.h1.l1
    gload16(bG,                    stDst + 32768);               // B q0
    gload16(bG +  64 * Cdim,       stDst + 32768 + 8192);        // B q1
    gload16(bG + 128 * Cdim,       stDst + 32768 + 16384);       // B q2
    gload16(bG + 192 * Cdim,       stDst + 32768 + 16384 + 8192);// B q3
    gload16(aG +  64 * Cdim,       stDst + 8192);                // A.h0.l2
    gload16(aG + 192 * Cdim,       stDst + 16384 + 8192);        // A.h1.l2
    VMW(0);
    BARRIER();

    int k0 = 64;                                   // staging k for tile t+1
    #pragma unroll 1
    for (int t = 0; t < 15; ++t, k0 += 64) {
        const int cb = (t & 1) * 65536;            // consume buffer
        char* nDst = stDst + (65536 - cb);         // stage buffer (t+1)

        // ---- phase 1: quad(0,0); stage A.h0.l1 + A.h1.l1 (t+1) ----
        #pragma unroll
        for (int i = 0; i < 4; ++i) {
            aF[i][0] = *(const bf16x8*)(aRd + cb + i * 2048 + x0);
            aF[i][1] = *(const bf16x8*)(aRd + cb + i * 2048 + (x0 ^ 64));
        }
        #pragma unroll
        for (int j = 0; j < 2; ++j) {
            bF[j][0] = *(const bf16x8*)(bRd + cb + j * 2048 + x0);
            bF[j][1] = *(const bf16x8*)(bRd + cb + j * 2048 + (x0 ^ 64));
        }
        gload16(aG + k0,              nDst);
        gload16(aG + 128 * Cdim + k0, nDst + 16384);
        BARRIER(); LGKM0();
        mma_quad<0, 0>(acc, aF, bF);
        BARRIER();

        // ---- phase 2: quad(0,1); stage B q0,q1; counted wait retires A.l2(t) ----
        #pragma unroll
        for (int j = 2; j < 4; ++j) {
            bF[j][0] = *(const bf16x8*)(bRd + cb + j * 2048 + x0);
            bF[j][1] = *(const bf16x8*)(bRd + cb + j * 2048 + (x0 ^ 64));
        }
        gload16(bG + k0,              nDst + 32768);
        gload16(bG +  64 * Cdim + k0, nDst + 32768 + 8192);
        VMW(4);
        BARRIER(); LGKM0();
        mma_quad<0, 2>(acc, aF, bF);
        BARRIER();

        // ---- phase 3: quad(1,0); stage B q2,q3 ----
        #pragma unroll
        for (int i = 0; i < 4; ++i) {
            aF[i][0] = *(const bf16x8*)(aRd + cb + (4 + i) * 2048 + x0);
            aF[i][1] = *(const bf16x8*)(aRd + cb + (4 + i) * 2048 + (x0 ^ 64));
        }
        gload16(bG + 128 * Cdim + k0, nDst + 32768 + 16384);
        gload16(bG + 192 * Cdim + k0, nDst + 32768 + 16384 + 8192);
        BARRIER(); LGKM0();
        mma_quad<4, 0>(acc, aF, bF);
        BARRIER();

        // ---- phase 4: quad(1,1); stage A.l2s; VMW(2) leaves A.l2(t+1) in flight ----
        gload16(aG +  64 * Cdim + k0, nDst + 8192);
        gload16(aG + 192 * Cdim + k0, nDst + 16384 + 8192);
        VMW(2);
        BARRIER();
        mma_quad<4, 2>(acc, aF, bF);
        BARRIER();
    }

    // ---- tail: K-tile 15 (buf1), no staging ----
    {
        const int cb = 65536;
        #pragma unroll
        for (int i = 0; i < 4; ++i) {
            aF[i][0] = *(const bf16x8*)(aRd + cb + i * 2048 + x0);
            aF[i][1] = *(const bf16x8*)(aRd + cb + i * 2048 + (x0 ^ 64));
        }
        #pragma unroll
        for (int j = 0; j < 2; ++j) {
            bF[j][0] = *(const bf16x8*)(bRd + cb + j * 2048 + x0);
            bF[j][1] = *(const bf16x8*)(bRd + cb + j * 2048 + (x0 ^ 64));
        }
        BARRIER(); LGKM0();
        mma_quad<0, 0>(acc, aF, bF);
        BARRIER();
        #pragma unroll
        for (int j = 2; j < 4; ++j) {
            bF[j][0] = *(const bf16x8*)(bRd + cb + j * 2048 + x0);
            bF[j][1] = *(const bf16x8*)(bRd + cb + j * 2048 + (x0 ^ 64));
        }
        VMW(0);   // retire A.l2(15) before the row-64..127 reads below
        BARRIER(); LGKM0();
        mma_quad<0, 2>(acc, aF, bF);
        BARRIER();
        #pragma unroll
        for (int i = 0; i < 4; ++i) {
            aF[i][0] = *(const bf16x8*)(aRd + cb + (4 + i) * 2048 + x0);
            aF[i][1] = *(const bf16x8*)(aRd + cb + (4 + i) * 2048 + (x0 ^ 64));
        }
        LGKM0();
        mma_quad<4, 0>(acc, aF, bF);
        mma_quad<4, 2>(acc, aF, bF);
    }
}

// ---------- GEMM1: [V|R] = X @ [Wv;Wr]^T, N=2048, sigmoid on R half ----------
__global__ __launch_bounds__(512, 2)
void gemm_vr(const u16* __restrict__ A, const u16* __restrict__ Wvr,
             u16* __restrict__ Vb, u16* __restrict__ Rb)
{
    __shared__ alignas(16) char smem[131072];
    const int wave = threadIdx.x >> 6;
    const int lane = threadIdx.x & 63;

    // bijective XCD swizzle: 512 blocks, 8 XCDs, 64 m-tiles x 8 n-tiles
    const int b    = blockIdx.x;
    const int xcd  = b & 7;
    const int sIdx = b >> 3;                 // 0..63
    const int mt   = xcd * 8 + (sIdx >> 3);  // 0..63
    const int nt   = sIdx & 7;               // 0..7

    f32x4 acc[8][4] = {};
    gemm_core(A, Wvr, smem, acc, mt * 256, nt * 256, wave, lane);

    const int l15 = lane & 15, g = lane >> 4;
    const bool isR = (nt >= 4);
    u16* dst = isR ? Rb : Vb;
    const int cbase = nt * 256 - (isR ? 1024 : 0) + (wave & 3) * 64 + l15;
    const int rbase = mt * 256 + (wave >> 2) * 128 + g * 4;
    #pragma unroll
    for (int i = 0; i < 8; ++i)
        #pragma unroll
        for (int j = 0; j < 4; ++j)
            #pragma unroll
            for (int r = 0; r < 4; ++r) {
                float v = acc[i][j][r];
                if (isR) v = 1.f / (1.f + __expf(-v));
                dst[(size_t)(rbase + i * 16 + r) * Cdim + cbase + j * 16] = f2bf(v);
            }
}

// ---------- GEMM2: out = Y @ Wo^T, N=1024, fp32 out ----------
__global__ __launch_bounds__(512, 2)
void gemm_out(const u16* __restrict__ A, const u16* __restrict__ Wo,
              float* __restrict__ O)
{
    __shared__ alignas(16) char smem[131072];
    const int wave = threadIdx.x >> 6;
    const int lane = threadIdx.x & 63;

    // 256 blocks, 64 m-tiles x 4 n-tiles
    const int b    = blockIdx.x;
    const int xcd  = b & 7;
    const int sIdx = b >> 3;                 // 0..31
    const int mt   = xcd * 8 + (sIdx >> 2);  // 0..63
    const int nt   = sIdx & 3;               // 0..3

    f32x4 acc[8][4] = {};
    gemm_core(A, Wo, smem, acc, mt * 256, nt * 256, wave, lane);

    const int l15 = lane & 15, g = lane >> 4;
    const int cbase = nt * 256 + (wave & 3) * 64 + l15;
    const int rbase = mt * 256 + (wave >> 2) * 128 + g * 4;
    #pragma unroll
    for (int i = 0; i < 8; ++i)
        #pragma unroll
        for (int j = 0; j < 4; ++j)
            #pragma unroll
            for (int r = 0; r < 4; ++r)
                O[(size_t)(rbase + i * 16 + r) * Cdim + cbase + j * 16] = acc[i][j][r];
}

// ---------- WKV: constant-coefficient linear recurrence, chunk-parallel ----------
__global__ __launch_bounds__(256)
void wkv_pass1(const u16* __restrict__ Vb, const float* __restrict__ td,
               float* __restrict__ Sa)
{
    const int t = blockIdx.x * 256 + threadIdx.x;     // 0..131071
    const int c     = t & (Cdim - 1);
    const int chunk = (t >> 10) & (NCH - 1);
    const int b     = t >> 14;

    const float tdc = td[c];
    const float lam = __expf(-fmaxf(tdc, 0.f));
    const float mu  = __expf(fminf(tdc, 0.f));

    size_t idx = ((size_t)(b * Tn + chunk * CLEN)) * Cdim + c;
    float s = 0.f;
    for (int i = 0; i < CLEN; ++i, idx += Cdim)
        s = lam * s + mu * bf2f(Vb[idx]);
    Sa[t] = s;
}

__global__ __launch_bounds__(256)
void wkv_pass2(const u16* __restrict__ Vb, const u16* __restrict__ Rb,
               const float* __restrict__ td, const float* __restrict__ tf,
               const float* __restrict__ Sa, u16* __restrict__ Y)
{
    const int t = blockIdx.x * 256 + threadIdx.x;
    const int c     = t & (Cdim - 1);
    const int chunk = (t >> 10) & (NCH - 1);
    const int b     = t >> 14;

    const float tdc = td[c], tfc = tf[c];
    const float lam  = __expf(-fmaxf(tdc, 0.f));
    const float mu   = __expf(fminf(tdc, 0.f));
    const float e1   = __expf(-fmaxf(tfc, 0.f));
    const float e2   = __expf(fminf(tfc, 0.f));
    const float lamL = __expf(-(float)CLEN * fmaxf(tdc, 0.f));
    const float Sb   = (fabsf(1.f - lam) < 1e-9f) ? mu * (float)CLEN
                                                  : mu * (1.f - lamL) / (1.f - lam);

    float aa = 0.f, bb = 0.f;
    for (int j = 0; j < chunk; ++j) {
        aa = lamL * aa + Sa[(size_t)b * (NCH * Cdim) + j * Cdim + c];
        bb = lamL * bb + Sb;
    }

    size_t idx = ((size_t)(b * Tn + chunk * CLEN)) * Cdim + c;
    for (int i = 0; i < CLEN; ++i, idx += Cdim) {
        const float v = bf2f(Vb[idx]);
        const float r = bf2f(Rb[idx]);
        const float wkv = (e1 * aa + e2 * v) / (e1 * bb + e2 + 1e-6f);
        Y[idx] = f2bf(r * wkv);
        aa = lam * aa + mu * v;
        bb = lam * bb + mu;
    }
}

extern "C" void kernel_launch(void* const* d_in, const int* in_sizes, int n_in,
                              void* d_out, int out_size, void* d_ws, size_t ws_size,
                              hipStream_t stream)
{
    // inputs: x, time_decay, time_first, key_w(dead), value_w, recep_w, out_w
    const float* x       = (const float*)d_in[0];
    const float* td      = (const float*)d_in[1];
    const float* tf      = (const float*)d_in[2];
    const float* value_w = (const float*)d_in[4];
    const float* recep_w = (const float*)d_in[5];
    const float* out_w   = (const float*)d_in[6];
    float* out = (float*)d_out;

    char* ws = (char*)d_ws;
    const size_t MB = 1024 * 1024;
    u16*   Xb  = (u16*)(ws);               // 32 MB; reused as Yb after gemm_vr+wkv
    u16*   Vb  = (u16*)(ws + 32 * MB);     // 32 MB
    u16*   Rb  = (u16*)(ws + 64 * MB);     // 32 MB
    u16*   Wvr = (u16*)(ws + 96 * MB);     //  4 MB  (concat [Wv; Wr], 2048 x 1024)
    u16*   Wo  = (u16*)(ws + 100 * MB);    //  2 MB
    float* Sa  = (float*)(ws + 102 * MB);  //  0.5 MB [8][16][1024]
    u16*   Yb  = Xb;                       // alias: Xb dead after gemm_vr

    const int nX4 = (Mrows * Cdim) / 4;   // 4194304
    const int nW4 = (Cdim * Cdim) / 4;    // 262144
    cast_f32_bf16<<<nX4 / 256, 256, 0, stream>>>(x, Xb, nX4);
    cast_weights<<<dim3(nW4 / 256, 3), 256, 0, stream>>>(value_w, recep_w, out_w,
                                                         Wvr, Wvr + 1024 * 1024, Wo);

    gemm_vr<<<512, 512, 0, stream>>>(Xb, Wvr, Vb, Rb);

    const int nScan = Bn * NCH * Cdim;    // 131072 threads
    wkv_pass1<<<nScan / 256, 256, 0, stream>>>(Vb, td, Sa);
    wkv_pass2<<<nScan / 256, 256, 0, stream>>>(Vb, Rb, td, tf, Sa, Yb);

    gemm_out<<<256, 512, 0, stream>>>(Yb, Wo, out);
}